// Round 18
// baseline (142.745 us; speedup 1.0000x reference)
//
#include <hip/hip_runtime.h>

// CIN_51539607712 — R19: the CLEAN occupancy experiment.
// R13/R14 calibration: effective MFMA cost ~19.4cy/SIMD at 2 waves/SIMD vs
// 4.85cy ubench (8 waves) -> matrix pipe is ISSUE-STARVED at 2 waves.
// Both prior occupancy tests were confounded: R6 halved per-wave-h MFMA
// (ratio trap); R12 used __launch_bounds__(512,2) whose 2nd arg let VGPR+
// AGPR (84+~48, unified file) exceed 128 -> 2nd block never resident.
// R19 = R12 geometry + R18 fence-free direct-load loop + (512,4):
// grid 512 = 256 r-tiles x 2 col-halves; block 64r x 64c, 8 waves =
// 4 kh (K/4) x 2 nq (32 cols). Per-wave per-h IDENTICAL to R18 (2 B-loads,
// 4 xl, 8 MFMA, 8 f32x4 fma); h-steps/wave = NT/4. LDS 64KB x 2 = 128KB;
// (512,4) caps unified VGPR at 128 -> 2 blocks/CU = 4 waves/SIMD real.
// Epilogue: R12's verified 4-way partial reduction.
// Numerics = R14 (1-MFMA RNE, absmax 0.125 vs thr 0.4525).
// out[r,n] = sum_h xl[r,h] * Y_h[r,n],  Y_h[r,n] = sum_m x0[r,m] W[h*32+m,n].

typedef unsigned int u32;
typedef __attribute__((ext_vector_type(8))) short short8;
typedef __attribute__((ext_vector_type(4))) float f32x4;
typedef __attribute__((ext_vector_type(4))) u32 u32x4;

#define R_TOTAL 16384

union PackU { u32 u[4]; short8 s; };
union PackB { u32x4 v; short8 s; };

// pack with round-to-nearest-even (both x0 fragments and W prep)
__device__ __forceinline__ u32 pack_rne(float a, float b) {
  u32 r;
  asm("v_cvt_pk_bf16_f32 %0, %1, %2" : "=v"(r) : "v"(a), "v"(b));
  return r;
}

// ---------------- fused prep kernel ----------------
// blocks 0..127: build X0T[m][b*16+d] = in[b][m][d]  (32 x 16384)
// blocks 128..255 / 256..767 / 768..1279: swizzle W0 / W1 / W2.
__device__ __forceinline__ void build_x0t_body(const float* __restrict__ in,
                                               float* __restrict__ x0t,
                                               int bid, int tid, float* t) {
  const int b0 = bid * 8;
  #pragma unroll
  for (int rep = 0; rep < 4; ++rep) {
    int idx = tid + rep * 256;
    *(float4*)&t[idx * 4] = *(const float4*)&in[(size_t)b0 * 512 + idx * 4];
  }
  __syncthreads();
  #pragma unroll
  for (int rep = 0; rep < 4; ++rep) {
    int idx = tid + rep * 256;     // 0..1023: m(32) x bl(8) x dq(4)
    int m = idx >> 5, rem = idx & 31;
    int bl = rem >> 2, dq = rem & 3;
    *(float4*)&x0t[(size_t)m * R_TOTAL + (b0 + bl) * 16 + dq * 4] =
        *(const float4*)&t[bl * 512 + m * 16 + dq * 4];
  }
}

// Block (t = bid>>2, nq = bid&3). 2 KB image: [nl 0..31][p 0..3] 16B blocks;
// position p holds logical block q = p ^ (nl&3); block q = RNE-packed
// W[t*32+q*8+j][nq*32+nl], j pairs packed (even=lo half, odd=hi half).
__device__ __forceinline__ void swizzle_body(const float* __restrict__ W,
                                             u32* __restrict__ wt,
                                             int bid, int tid, float* wl) {
  const int t = bid >> 2, nq = bid & 3;
  {
    int kk = tid >> 3, c4 = tid & 7;
    float4 v = *(const float4*)&W[(size_t)(t * 32 + kk) * 128 + nq * 32 + c4 * 4];
    wl[kk * 33 + c4 * 4 + 0] = v.x;
    wl[kk * 33 + c4 * 4 + 1] = v.y;
    wl[kk * 33 + c4 * 4 + 2] = v.z;
    wl[kk * 33 + c4 * 4 + 3] = v.w;
  }
  __syncthreads();
  if (tid < 128) {
    int nl = tid >> 2, p = tid & 3;
    int q = p ^ (nl & 3);
    u32 o[4];
    #pragma unroll
    for (int jj = 0; jj < 4; ++jj)
      o[jj] = pack_rne(wl[(q * 8 + 2 * jj + 0) * 33 + nl],
                       wl[(q * 8 + 2 * jj + 1) * 33 + nl]);
    *(u32x4*)(wt + (size_t)(t * 4 + nq) * 512 + nl * 16 + p * 4) =
        u32x4{o[0], o[1], o[2], o[3]};
  }
}

__global__ __launch_bounds__(256) void prep_all(
    const float* __restrict__ in, float* __restrict__ x0t,
    const float* __restrict__ W0, u32* __restrict__ wt0,
    const float* __restrict__ W1, u32* __restrict__ wt1,
    const float* __restrict__ W2, u32* __restrict__ wt2) {
  __shared__ float sh[4096];
  const int b = blockIdx.x, tid = threadIdx.x;
  if (b < 128)      build_x0t_body(in, x0t, b, tid, sh);
  else if (b < 256) swizzle_body(W0, wt0, b - 128, tid, sh);
  else if (b < 768) swizzle_body(W1, wt1, b - 256, tid, sh);
  else              swizzle_body(W2, wt2, b - 768, tid, sh);
}

// KITER(I): h-tile t0+I, SLOT = I&1, BP = this parity's B-frag regs.
// Plain C (R18): consume BP/xn[SLOT], then refill with tile I+2's loads.
// No waits / sched_barriers / setprio — data deps carry the hazards.
#define KITER(I, SLOT, DO_ISSUE, BP)                                           \
  {                                                                            \
    f32x4 Y0[4], Y1[4];                                                        \
    _Pragma("unroll")                                                          \
    for (int f = 0; f < 4; ++f)                                                \
      Y0[f] = __builtin_amdgcn_mfma_f32_16x16x32_bf16(Ah[f].s, BP[0].s, zero4, 0, 0, 0); \
    _Pragma("unroll")                                                          \
    for (int f = 0; f < 4; ++f) {                                              \
      acc[f][0] += xn[SLOT][f] * Y0[f];                                        \
    }                                                                          \
    _Pragma("unroll")                                                          \
    for (int f = 0; f < 4; ++f)                                                \
      Y1[f] = __builtin_amdgcn_mfma_f32_16x16x32_bf16(Ah[f].s, BP[1].s, zero4, 0, 0, 0); \
    _Pragma("unroll")                                                          \
    for (int f = 0; f < 4; ++f) {                                              \
      acc[f][1] += xn[SLOT][f] * Y1[f];                                        \
    }                                                                          \
    if (DO_ISSUE) {                                                            \
      const u32* ib = wt + (size_t)((t0 + (I) + 2) * 4 + nqg) * 512;           \
      BP[0].v = *(const u32x4*)(ib + boff0);                                   \
      BP[1].v = *(const u32x4*)(ib + boff1);                                   \
      const float* xp = xt + (size_t)(t0 + (I) + 2) * R_TOTAL + r0;            \
      xn[SLOT][0] = *(const f32x4*)(xp + 0 + q * 4);                           \
      xn[SLOT][1] = *(const f32x4*)(xp + 16 + q * 4);                          \
      xn[SLOT][2] = *(const f32x4*)(xp + 32 + q * 4);                          \
      xn[SLOT][3] = *(const f32x4*)(xp + 48 + q * 4);                          \
    }                                                                          \
  }

// ---------------- main layer kernel ----------------
// Block 64 rows x 64 cols, 8 waves: kh = w>>1 (K quarter), nq = w&1.
// Global col quarter nqg = (bid&1)*2 + nq. Grid 512, 64 KB static LDS,
// __launch_bounds__(512,4) -> unified VGPR cap 128 -> 2 blocks/CU resident.
template <int NT, bool RELU, bool STORE_X>
__global__ __launch_bounds__(512, 4) void layer_mfma(
    const float* __restrict__ xt,    // NT x R (transposed prev activation)
    const float* __restrict__ x0t,   // 32 x R
    const u32* __restrict__ wt,      // NT*4 quarter images (512 u32 each)
    const float* __restrict__ bias,  // 128
    float* __restrict__ xoutT,       // 128 x R (if STORE_X)
    float* __restrict__ osum)        // d_out + layer offset, stride 384
{
  constexpr int HT = NT / 4;
  static_assert((HT & 1) == 0 && HT >= 4, "pair-loop needs even HT >= 4");
  __shared__ u32 smem[16384];        // 64 KB: 8 waves x 2048 u32 (epilogue)

  const int tid = threadIdx.x;
  const int w = tid >> 6, lane = tid & 63;
  const int ln15 = lane & 15, q = lane >> 4;
  const int kh = w >> 1, nq = w & 1;
  const int r0 = (blockIdx.x >> 1) * 64;
  const int nqg = (blockIdx.x & 1) * 2 + nq;   // global col quarter 0..3
  const int sw = ln15 & 3;           // matches prep's 4-position XOR layout
  u32* mybuf = smem + w * 2048;

  // per-lane B-frag offsets within a 512-u32 image (loop-invariant)
  const int boff0 = ln15 * 16 + ((q ^ sw) * 4);
  const int boff1 = (16 + ln15) * 16 + ((q ^ sw) * 4);

  // ---- loop-invariant A fragments: RNE-rounded x0 rows (A[i=ln15][k=q*8+j])
  PackU Ah[4];
  #pragma unroll
  for (int f = 0; f < 4; ++f) {
    const int rbase = r0 + f * 16 + ln15;
    float e[8];
    #pragma unroll
    for (int j = 0; j < 8; ++j) e[j] = x0t[(size_t)(q * 8 + j) * R_TOTAL + rbase];
    #pragma unroll
    for (int jj = 0; jj < 4; ++jj)
      Ah[f].u[jj] = pack_rne(e[2 * jj], e[2 * jj + 1]);
  }

  f32x4 acc[4][2];
  #pragma unroll
  for (int f = 0; f < 4; ++f)
    #pragma unroll
    for (int c = 0; c < 2; ++c) acc[f][c] = f32x4{0.f, 0.f, 0.f, 0.f};
  const f32x4 zero4 = {0.f, 0.f, 0.f, 0.f};

  const int t0 = kh * HT;

  // ---- prologue: load group(0) into (ba, xn[0]), group(1) into (bb, xn[1])
  PackB ba[2], bb[2];
  f32x4 xn[2][4];
  {
    const u32* ib = wt + (size_t)(t0 * 4 + nqg) * 512;
    ba[0].v = *(const u32x4*)(ib + boff0);
    ba[1].v = *(const u32x4*)(ib + boff1);
    const float* xp = xt + (size_t)t0 * R_TOTAL + r0;
    xn[0][0] = *(const f32x4*)(xp + 0 + q * 4);
    xn[0][1] = *(const f32x4*)(xp + 16 + q * 4);
    xn[0][2] = *(const f32x4*)(xp + 32 + q * 4);
    xn[0][3] = *(const f32x4*)(xp + 48 + q * 4);
  }
  {
    const u32* ib = wt + (size_t)((t0 + 1) * 4 + nqg) * 512;
    bb[0].v = *(const u32x4*)(ib + boff0);
    bb[1].v = *(const u32x4*)(ib + boff1);
    const float* xp = xt + (size_t)(t0 + 1) * R_TOTAL + r0;
    xn[1][0] = *(const f32x4*)(xp + 0 + q * 4);
    xn[1][1] = *(const f32x4*)(xp + 16 + q * 4);
    xn[1][2] = *(const f32x4*)(xp + 32 + q * 4);
    xn[1][3] = *(const f32x4*)(xp + 48 + q * 4);
  }

  // ---- steady state: consume slot, refill with tile i+2 ----
  for (int i = 0; i < HT - 2; i += 2) {
    KITER(i,     0, 1, ba);
    KITER(i + 1, 1, 1, bb);
  }
  // ---- peeled last pair: no refill ----
  KITER(HT - 2, 0, 0, ba);
  KITER(HT - 1, 1, 0, bb);

  // ---------------- epilogue: 4-way partial reduction (R12-verified) -------
  __syncthreads();
  if (kh != 0) {                    // dump partial acc into own region (8 KB)
    u32* reg = mybuf;
    #pragma unroll
    for (int f = 0; f < 4; ++f)
      #pragma unroll
      for (int c = 0; c < 2; ++c)
        *(f32x4*)(reg + ((size_t)(f * 2 + c) * 64 + lane) * 4) = acc[f][c];
  }
  __syncthreads();
  if (kh == 0) {
    float bs[2];
    #pragma unroll
    for (int c = 0; c < 2; ++c) bs[c] = bias[nqg * 32 + c * 16 + ln15];

    f32x4 vv[4][2];
    #pragma unroll
    for (int f = 0; f < 4; ++f) {
      #pragma unroll
      for (int c = 0; c < 2; ++c) {
        f32x4 v = acc[f][c];
        #pragma unroll
        for (int p = 1; p < 4; ++p) {     // partners w+2p (kh=1..3, same nq)
          const u32* reg = smem + (size_t)(w + 2 * p) * 2048;
          v += *(const f32x4*)(reg + ((size_t)(f * 2 + c) * 64 + lane) * 4);
        }
        v.x += bs[c]; v.y += bs[c]; v.z += bs[c]; v.w += bs[c];
        if (RELU) {
          v.x = fmaxf(v.x, 0.f); v.y = fmaxf(v.y, 0.f);
          v.z = fmaxf(v.z, 0.f); v.w = fmaxf(v.w, 0.f);
        }
        vv[f][c] = v;
        float s = v.x + v.y + v.z + v.w;       // 4 rows of batch (r0>>4)+f
        s += __shfl_xor(s, 16, 64);
        s += __shfl_xor(s, 32, 64);
        if (q == 0)
          osum[(size_t)((r0 >> 4) + f) * 384 + nqg * 32 + c * 16 + ln15] = s;
      }
    }

    if (STORE_X) {
      // transpose via own LDS region (free for kh==0), 64B stores to XT.
      u32* myreg = mybuf;
      #pragma unroll
      for (int f = 0; f < 4; ++f)
        #pragma unroll
        for (int c = 0; c < 2; ++c)
          *(f32x4*)(myreg + ((size_t)(f * 2 + c) * 64 + lane) * 4) = vv[f][c];
      // element (r_local, lcol): frag (f=r>>4, c=lcol>>4), lane q=(r>>2)&3,
      // ln15=lcol&15, comp rr=r&3. Round (c,s): lane -> col=c*16+(lane>>2),
      // r_local = s*16 + (lane&3)*4.
      #pragma unroll
      for (int c = 0; c < 2; ++c) {
        #pragma unroll
        for (int s = 0; s < 4; ++s) {
          f32x4 vr = *(const f32x4*)(myreg +
              ((size_t)(s * 2 + c) * 64 + (lane & 3) * 16 + (lane >> 2)) * 4);
          const int col = nqg * 32 + c * 16 + (lane >> 2);
          *(f32x4*)&xoutT[(size_t)col * R_TOTAL + r0 + s * 16 + (lane & 3) * 4] = vr;
        }
      }
    }
  }
}

extern "C" void kernel_launch(void* const* d_in, const int* in_sizes, int n_in,
                              void* d_out, int out_size, void* d_ws, size_t ws_size,
                              hipStream_t stream) {
  const float* in = (const float*)d_in[0];
  const float* W0 = (const float*)d_in[1];
  const float* b0 = (const float*)d_in[2];
  const float* W1 = (const float*)d_in[3];
  const float* b1 = (const float*)d_in[4];
  const float* W2 = (const float*)d_in[5];
  const float* b2 = (const float*)d_in[6];
  float* out = (float*)d_out;

  float* X0T = (float*)d_ws;                         // 32 x 16384   (2 MB)
  float* X1T = X0T + (size_t)32 * R_TOTAL;           // 128 x 16384  (8 MB)
  float* X2T = X1T + (size_t)128 * R_TOTAL;          // 128 x 16384  (8 MB)
  u32* Wt0 = (u32*)(X2T + (size_t)128 * R_TOTAL);    // 32*4*512 u32   (256 KB)
  u32* Wt1 = Wt0 + (size_t)32 * 4 * 512;             // 128*4*512 u32  (1 MB)
  u32* Wt2 = Wt1 + (size_t)128 * 4 * 512;            // 128*4*512 u32  (1 MB)
  // total ws: ~20.3 MB

  prep_all<<<1280, 256, 0, stream>>>(in, X0T, W0, Wt0, W1, Wt1, W2, Wt2);

  layer_mfma<32, true, true><<<512, 512, 0, stream>>>(X0T, X0T, Wt0, b0, X1T, out + 0);
  layer_mfma<128, true, true><<<512, 512, 0, stream>>>(X1T, X0T, Wt1, b1, X2T, out + 128);
  layer_mfma<128, false, false><<<512, 512, 0, stream>>>(X2T, X0T, Wt2, b2, nullptr, out + 256);
}

// Round 19
// 129.618 us; speedup vs baseline: 1.1013x; 1.1013x over previous
//
#include <hip/hip_runtime.h>

// CIN_51539607712 — R20: fold xl INTO the MFMA A-operand (z-GEMM form).
// 16 rounds of scheduling levers left a ~344cy/wave-h stall; R19's counters
// closed the occupancy route (VGPR cap). Fresh-eyes diagnosis: the inner
// dataflow "Y = mfma(); acc += xl*Y" makes EVERY MFMA result a VALU input —
// a dependency no real GEMM has (GEMMs chain through the MFMA C operand at
// ~100% util; our MfmaUtil ~30 + VALUBusy ~28 ping-pong is the signature).
// Algebra fix: out[r,n] = sum_{h,m} (xl[r,h]*x0[r,m]) * W[hm,n] — a plain
// GEMM with A-panel z[r,hm] = xl[r,h]*x0[r,m], built per-h in registers:
// per frag 8 v_mul_f32 + 4 v_cvt_pk_bf16_f32 (xl = ONE scalar/lane at A-row
// ln15; x0 rows resident in fp32, 32 VGPR). acc = mfma(z, B, acc) — pure
// C-chained MFMAs; z(h+1) formation overlaps MFMA(h) on the VALU pipe.
// Numerics: rne(xl*x0) one 2^-9-rel rounding replaces rne(x0) — same
// magnitude; expect absmax ~0.125-0.19 vs thr 0.4525. W images, prep,
// epilogue, R18 geometry (grid 256, 512thr, 8 waves kh=w&1/nq=w>>1, 64-row
// blocks) and the fence-free direct-load ledger all unchanged.
// out[r,n] = sum_h xl[r,h] * sum_m x0[r,m] W[h*32+m,n].

typedef unsigned int u32;
typedef __attribute__((ext_vector_type(8))) short short8;
typedef __attribute__((ext_vector_type(4))) float f32x4;
typedef __attribute__((ext_vector_type(4))) u32 u32x4;

#define R_TOTAL 16384

union PackU { u32 u[4]; short8 s; };
union PackB { u32x4 v; short8 s; };

// pack with round-to-nearest-even
__device__ __forceinline__ u32 pack_rne(float a, float b) {
  u32 r;
  asm("v_cvt_pk_bf16_f32 %0, %1, %2" : "=v"(r) : "v"(a), "v"(b));
  return r;
}

// ---------------- fused prep kernel ----------------
// blocks 0..127: build X0T[m][b*16+d] = in[b][m][d]  (32 x 16384)
// blocks 128..255 / 256..767 / 768..1279: swizzle W0 / W1 / W2.
__device__ __forceinline__ void build_x0t_body(const float* __restrict__ in,
                                               float* __restrict__ x0t,
                                               int bid, int tid, float* t) {
  const int b0 = bid * 8;
  #pragma unroll
  for (int rep = 0; rep < 4; ++rep) {
    int idx = tid + rep * 256;
    *(float4*)&t[idx * 4] = *(const float4*)&in[(size_t)b0 * 512 + idx * 4];
  }
  __syncthreads();
  #pragma unroll
  for (int rep = 0; rep < 4; ++rep) {
    int idx = tid + rep * 256;     // 0..1023: m(32) x bl(8) x dq(4)
    int m = idx >> 5, rem = idx & 31;
    int bl = rem >> 2, dq = rem & 3;
    *(float4*)&x0t[(size_t)m * R_TOTAL + (b0 + bl) * 16 + dq * 4] =
        *(const float4*)&t[bl * 512 + m * 16 + dq * 4];
  }
}

// Block (t = bid>>2, nq = bid&3). 2 KB image: [nl 0..31][p 0..3] 16B blocks;
// position p holds logical block q = p ^ (nl&3); block q = RNE-packed
// W[t*32+q*8+j][nq*32+nl], j pairs packed (even=lo half, odd=hi half).
__device__ __forceinline__ void swizzle_body(const float* __restrict__ W,
                                             u32* __restrict__ wt,
                                             int bid, int tid, float* wl) {
  const int t = bid >> 2, nq = bid & 3;
  {
    int kk = tid >> 3, c4 = tid & 7;
    float4 v = *(const float4*)&W[(size_t)(t * 32 + kk) * 128 + nq * 32 + c4 * 4];
    wl[kk * 33 + c4 * 4 + 0] = v.x;
    wl[kk * 33 + c4 * 4 + 1] = v.y;
    wl[kk * 33 + c4 * 4 + 2] = v.z;
    wl[kk * 33 + c4 * 4 + 3] = v.w;
  }
  __syncthreads();
  if (tid < 128) {
    int nl = tid >> 2, p = tid & 3;
    int q = p ^ (nl & 3);
    u32 o[4];
    #pragma unroll
    for (int jj = 0; jj < 4; ++jj)
      o[jj] = pack_rne(wl[(q * 8 + 2 * jj + 0) * 33 + nl],
                       wl[(q * 8 + 2 * jj + 1) * 33 + nl]);
    *(u32x4*)(wt + (size_t)(t * 4 + nq) * 512 + nl * 16 + p * 4) =
        u32x4{o[0], o[1], o[2], o[3]};
  }
}

__global__ __launch_bounds__(256) void prep_all(
    const float* __restrict__ in, float* __restrict__ x0t,
    const float* __restrict__ W0, u32* __restrict__ wt0,
    const float* __restrict__ W1, u32* __restrict__ wt1,
    const float* __restrict__ W2, u32* __restrict__ wt2) {
  __shared__ float sh[4096];
  const int b = blockIdx.x, tid = threadIdx.x;
  if (b < 128)      build_x0t_body(in, x0t, b, tid, sh);
  else if (b < 256) swizzle_body(W0, wt0, b - 128, tid, sh);
  else if (b < 768) swizzle_body(W1, wt1, b - 256, tid, sh);
  else              swizzle_body(W2, wt2, b - 768, tid, sh);
}

// KITER(I): h-tile t0+I, SLOT = I&1, BP = this parity's B-frag regs.
// Build z-frags (xl scalar x resident fp32 x0 rows, RNE-pack), then
// C-chained MFMAs into acc. Refill BP + xl scalar for tile I+2.
// No manual waits — data deps carry the hazards (R18).
#define KITER(I, SLOT, DO_ISSUE, BP)                                           \
  {                                                                            \
    PackU Z[4];                                                                \
    _Pragma("unroll")                                                          \
    for (int f = 0; f < 4; ++f) {                                              \
      const float xs = xls[SLOT][f];                                           \
      _Pragma("unroll")                                                        \
      for (int jj = 0; jj < 4; ++jj)                                           \
        Z[f].u[jj] = pack_rne(xs * x0v[f][2 * jj], xs * x0v[f][2 * jj + 1]);   \
    }                                                                          \
    _Pragma("unroll")                                                          \
    for (int f = 0; f < 4; ++f)                                                \
      acc[f][0] = __builtin_amdgcn_mfma_f32_16x16x32_bf16(Z[f].s, BP[0].s, acc[f][0], 0, 0, 0); \
    _Pragma("unroll")                                                          \
    for (int f = 0; f < 4; ++f)                                                \
      acc[f][1] = __builtin_amdgcn_mfma_f32_16x16x32_bf16(Z[f].s, BP[1].s, acc[f][1], 0, 0, 0); \
    if (DO_ISSUE) {                                                            \
      const u32* ib = wt + (size_t)((t0 + (I) + 2) * 4 + nq) * 512;            \
      BP[0].v = *(const u32x4*)(ib + boff0);                                   \
      BP[1].v = *(const u32x4*)(ib + boff1);                                   \
      const float* xp = xt + (size_t)(t0 + (I) + 2) * R_TOTAL + r0;            \
      xls[SLOT][0] = xp[0 + ln15];                                             \
      xls[SLOT][1] = xp[16 + ln15];                                            \
      xls[SLOT][2] = xp[32 + ln15];                                            \
      xls[SLOT][3] = xp[48 + ln15];                                            \
    }                                                                          \
  }

// ---------------- main layer kernel ----------------
template <int NT, bool RELU, bool STORE_X>
__global__ __launch_bounds__(512, 2) void layer_mfma(
    const float* __restrict__ xt,    // NT x R (transposed prev activation)
    const float* __restrict__ x0t,   // 32 x R
    const u32* __restrict__ wt,      // NT*4 quarter images (512 u32 each)
    const float* __restrict__ bias,  // 128
    float* __restrict__ xoutT,       // 128 x R (if STORE_X)
    float* __restrict__ osum)        // d_out + layer offset, stride 384
{
  constexpr int HT = NT / 2;
  static_assert((HT & 1) == 0 && HT >= 4, "pair-loop needs even HT >= 4");
  __shared__ u32 smem[16384];        // 64 KB: epilogue exchange only

  const int tid = threadIdx.x;
  const int w = tid >> 6, lane = tid & 63;
  const int ln15 = lane & 15, q = lane >> 4;
  const int kh = w & 1, nq = w >> 1;
  const int r0 = blockIdx.x * 64;
  const int sw = ln15 & 3;           // matches prep's 4-position XOR layout
  u32* mybuf = smem + w * 2048;

  // per-lane B-frag offsets within a 512-u32 image (loop-invariant)
  const int boff0 = ln15 * 16 + ((q ^ sw) * 4);
  const int boff1 = (16 + ln15) * 16 + ((q ^ sw) * 4);

  // ---- loop-invariant x0 rows in FP32 (A-rows i=ln15, k=q*8+j): 32 VGPR ----
  float x0v[4][8];
  #pragma unroll
  for (int f = 0; f < 4; ++f) {
    const int rbase = r0 + f * 16 + ln15;
    #pragma unroll
    for (int j = 0; j < 8; ++j)
      x0v[f][j] = x0t[(size_t)(q * 8 + j) * R_TOTAL + rbase];
  }

  f32x4 acc[4][2];
  #pragma unroll
  for (int f = 0; f < 4; ++f)
    #pragma unroll
    for (int c = 0; c < 2; ++c) acc[f][c] = f32x4{0.f, 0.f, 0.f, 0.f};

  const int t0 = kh * HT;

  // ---- prologue: group(0) -> (ba, xls[0]), group(1) -> (bb, xls[1]) ----
  PackB ba[2], bb[2];
  float xls[2][4];
  {
    const u32* ib = wt + (size_t)(t0 * 4 + nq) * 512;
    ba[0].v = *(const u32x4*)(ib + boff0);
    ba[1].v = *(const u32x4*)(ib + boff1);
    const float* xp = xt + (size_t)t0 * R_TOTAL + r0;
    xls[0][0] = xp[0 + ln15];
    xls[0][1] = xp[16 + ln15];
    xls[0][2] = xp[32 + ln15];
    xls[0][3] = xp[48 + ln15];
  }
  {
    const u32* ib = wt + (size_t)((t0 + 1) * 4 + nq) * 512;
    bb[0].v = *(const u32x4*)(ib + boff0);
    bb[1].v = *(const u32x4*)(ib + boff1);
    const float* xp = xt + (size_t)(t0 + 1) * R_TOTAL + r0;
    xls[1][0] = xp[0 + ln15];
    xls[1][1] = xp[16 + ln15];
    xls[1][2] = xp[32 + ln15];
    xls[1][3] = xp[48 + ln15];
  }

  // ---- steady state: consume slot, refill with tile i+2 ----
  for (int i = 0; i < HT - 2; i += 2) {
    KITER(i,     0, 1, ba);
    KITER(i + 1, 1, 1, bb);
  }
  // ---- peeled last pair: no refill ----
  KITER(HT - 2, 0, 0, ba);
  KITER(HT - 1, 1, 0, bb);

  // ---------------- epilogue ----------------
  __syncthreads();
  if (kh == 1) {                    // dump partial acc into own region (8 KB)
    u32* reg = mybuf;
    #pragma unroll
    for (int f = 0; f < 4; ++f)
      #pragma unroll
      for (int c = 0; c < 2; ++c)
        *(f32x4*)(reg + ((size_t)(f * 2 + c) * 64 + lane) * 4) = acc[f][c];
  }
  __syncthreads();
  if (kh == 0) {
    const u32* reg = smem + (w + 1) * 2048;   // partner (kh=1, same nq)
    float bs[2];
    #pragma unroll
    for (int c = 0; c < 2; ++c) bs[c] = bias[nq * 32 + c * 16 + ln15];

    f32x4 vv[4][2];
    #pragma unroll
    for (int f = 0; f < 4; ++f) {
      #pragma unroll
      for (int c = 0; c < 2; ++c) {
        f32x4 part = *(const f32x4*)(reg + ((size_t)(f * 2 + c) * 64 + lane) * 4);
        f32x4 v = acc[f][c] + part;
        v.x += bs[c]; v.y += bs[c]; v.z += bs[c]; v.w += bs[c];
        if (RELU) {
          v.x = fmaxf(v.x, 0.f); v.y = fmaxf(v.y, 0.f);
          v.z = fmaxf(v.z, 0.f); v.w = fmaxf(v.w, 0.f);
        }
        vv[f][c] = v;
        float s = v.x + v.y + v.z + v.w;       // 4 rows of batch (r0>>4)+f
        s += __shfl_xor(s, 16, 64);
        s += __shfl_xor(s, 32, 64);
        if (q == 0)
          osum[(size_t)((r0 >> 4) + f) * 384 + nq * 32 + c * 16 + ln15] = s;
      }
    }

    if (STORE_X) {
      // transpose via own LDS region, then 64B-contiguous stores to XT.
      u32* myreg = mybuf;
      #pragma unroll
      for (int f = 0; f < 4; ++f)
        #pragma unroll
        for (int c = 0; c < 2; ++c)
          *(f32x4*)(myreg + ((size_t)(f * 2 + c) * 64 + lane) * 4) = vv[f][c];
      // element (r_local, lcol): frag (f=r>>4, c=lcol>>4), lane q=(r>>2)&3,
      // ln15=lcol&15, comp rr=r&3. Round (c,s): lane -> col=c*16+(lane>>2),
      // r_local = s*16 + (lane&3)*4.
      #pragma unroll
      for (int c = 0; c < 2; ++c) {
        #pragma unroll
        for (int s = 0; s < 4; ++s) {
          f32x4 vr = *(const f32x4*)(myreg +
              ((size_t)(s * 2 + c) * 64 + (lane & 3) * 16 + (lane >> 2)) * 4);
          const int col = nq * 32 + c * 16 + (lane >> 2);
          *(f32x4*)&xoutT[(size_t)col * R_TOTAL + r0 + s * 16 + (lane & 3) * 4] = vr;
        }
      }
    }
  }
}

extern "C" void kernel_launch(void* const* d_in, const int* in_sizes, int n_in,
                              void* d_out, int out_size, void* d_ws, size_t ws_size,
                              hipStream_t stream) {
  const float* in = (const float*)d_in[0];
  const float* W0 = (const float*)d_in[1];
  const float* b0 = (const float*)d_in[2];
  const float* W1 = (const float*)d_in[3];
  const float* b1 = (const float*)d_in[4];
  const float* W2 = (const float*)d_in[5];
  const float* b2 = (const float*)d_in[6];
  float* out = (float*)d_out;

  float* X0T = (float*)d_ws;                         // 32 x 16384   (2 MB)
  float* X1T = X0T + (size_t)32 * R_TOTAL;           // 128 x 16384  (8 MB)
  float* X2T = X1T + (size_t)128 * R_TOTAL;          // 128 x 16384  (8 MB)
  u32* Wt0 = (u32*)(X2T + (size_t)128 * R_TOTAL);    // 32*4*512 u32   (256 KB)
  u32* Wt1 = Wt0 + (size_t)32 * 4 * 512;             // 128*4*512 u32  (1 MB)
  u32* Wt2 = Wt1 + (size_t)128 * 4 * 512;            // 128*4*512 u32  (1 MB)
  // total ws: ~20.3 MB

  prep_all<<<1280, 256, 0, stream>>>(in, X0T, W0, Wt0, W1, Wt1, W2, Wt2);

  layer_mfma<32, true, true><<<256, 512, 0, stream>>>(X0T, X0T, Wt0, b0, X1T, out + 0);
  layer_mfma<128, true, true><<<256, 512, 0, stream>>>(X1T, X0T, Wt1, b1, X2T, out + 128);
  layer_mfma<128, false, false><<<256, 512, 0, stream>>>(X2T, X0T, Wt2, b2, nullptr, out + 256);
}

// Round 20
// 128.526 us; speedup vs baseline: 1.1106x; 1.0085x over previous
//
#include <hip/hip_runtime.h>

// CIN_51539607712 — R21: R20 + xl-contiguous XT layout (6 -> 3 vmem/h).
// R20's z-GEMM left ~800cy/iter stall that survives early-issue (R17),
// compiler scheduling (R18), and MFMA-chain fixes (R20). Last untested
// suspect: vmem INSTRUCTION count (4 scalar xl dword loads per h, q-dup).
// Fix: permute XT rows within each 64-row group — row f*16+i15 stored at
// i15*4+f — so lane ln15's four per-h xl scalars are ONE dwordx4.
// Loads per wave-h: 2 B + 1 xl = 3 (was 6). XT is our own workspace;
// permutation touches build_x0t scatter, x0v index, xl load, STORE_X only.
// Numerics = R14/R20 (rne(xl*x0) z-frags, absmax 0.125 vs thr 0.4525).
// Geometry = R4 champion: grid 256, 512 thr, 8 waves (kh=w&1, nq=w>>1),
// 64-row blocks; fence-free direct-load depth-2 pipeline (R18).
// out[r,n] = sum_h xl[r,h] * sum_m x0[r,m] W[h*32+m,n].

typedef unsigned int u32;
typedef __attribute__((ext_vector_type(8))) short short8;
typedef __attribute__((ext_vector_type(4))) float f32x4;
typedef __attribute__((ext_vector_type(4))) u32 u32x4;

#define R_TOTAL 16384

union PackU { u32 u[4]; short8 s; };
union PackB { u32x4 v; short8 s; };

// pack with round-to-nearest-even
__device__ __forceinline__ u32 pack_rne(float a, float b) {
  u32 r;
  asm("v_cvt_pk_bf16_f32 %0, %1, %2" : "=v"(r) : "v"(a), "v"(b));
  return r;
}

// ---------------- fused prep kernel ----------------
// blocks 0..127: build X0T (permuted layout: within each 64-row group,
// logical row f*16+i15 stored at i15*4+f). blocks 128+: swizzle W0/W1/W2.
__device__ __forceinline__ void build_x0t_body(const float* __restrict__ in,
                                               float* __restrict__ x0t,
                                               int bid, int tid, float* t) {
  const int b0 = bid * 8;
  #pragma unroll
  for (int rep = 0; rep < 4; ++rep) {
    int idx = tid + rep * 256;
    *(float4*)&t[idx * 4] = *(const float4*)&in[(size_t)b0 * 512 + idx * 4];
  }
  __syncthreads();
  #pragma unroll
  for (int rep = 0; rep < 4; ++rep) {
    int idx = tid + rep * 256;     // 0..1023: m(32) x bl(8) x dq(4)
    int m = idx >> 5, rem = idx & 31;
    int bl = rem >> 2, dq = rem & 3;
    float4 v = *(const float4*)&t[bl * 512 + m * 16 + dq * 4];
    // logical rows r = (b0+bl)*16 + dq*4 + e; i15 = dq*4+e, f = (b0+bl)&3
    const int rb = b0 + bl;
    float* dst = &x0t[(size_t)m * R_TOTAL + (rb >> 2) * 64 + (rb & 3)];
    dst[(dq * 4 + 0) * 4] = v.x;
    dst[(dq * 4 + 1) * 4] = v.y;
    dst[(dq * 4 + 2) * 4] = v.z;
    dst[(dq * 4 + 3) * 4] = v.w;
  }
}

// Block (t = bid>>2, nq = bid&3). 2 KB image: [nl 0..31][p 0..3] 16B blocks;
// position p holds logical block q = p ^ (nl&3); block q = RNE-packed
// W[t*32+q*8+j][nq*32+nl], j pairs packed (even=lo half, odd=hi half).
__device__ __forceinline__ void swizzle_body(const float* __restrict__ W,
                                             u32* __restrict__ wt,
                                             int bid, int tid, float* wl) {
  const int t = bid >> 2, nq = bid & 3;
  {
    int kk = tid >> 3, c4 = tid & 7;
    float4 v = *(const float4*)&W[(size_t)(t * 32 + kk) * 128 + nq * 32 + c4 * 4];
    wl[kk * 33 + c4 * 4 + 0] = v.x;
    wl[kk * 33 + c4 * 4 + 1] = v.y;
    wl[kk * 33 + c4 * 4 + 2] = v.z;
    wl[kk * 33 + c4 * 4 + 3] = v.w;
  }
  __syncthreads();
  if (tid < 128) {
    int nl = tid >> 2, p = tid & 3;
    int q = p ^ (nl & 3);
    u32 o[4];
    #pragma unroll
    for (int jj = 0; jj < 4; ++jj)
      o[jj] = pack_rne(wl[(q * 8 + 2 * jj + 0) * 33 + nl],
                       wl[(q * 8 + 2 * jj + 1) * 33 + nl]);
    *(u32x4*)(wt + (size_t)(t * 4 + nq) * 512 + nl * 16 + p * 4) =
        u32x4{o[0], o[1], o[2], o[3]};
  }
}

__global__ __launch_bounds__(256) void prep_all(
    const float* __restrict__ in, float* __restrict__ x0t,
    const float* __restrict__ W0, u32* __restrict__ wt0,
    const float* __restrict__ W1, u32* __restrict__ wt1,
    const float* __restrict__ W2, u32* __restrict__ wt2) {
  __shared__ float sh[4096];
  const int b = blockIdx.x, tid = threadIdx.x;
  if (b < 128)      build_x0t_body(in, x0t, b, tid, sh);
  else if (b < 256) swizzle_body(W0, wt0, b - 128, tid, sh);
  else if (b < 768) swizzle_body(W1, wt1, b - 256, tid, sh);
  else              swizzle_body(W2, wt2, b - 768, tid, sh);
}

// KITER(I): h-tile t0+I, SLOT = I&1, BP = this parity's B-frag regs.
// Build z-frags (xl scalar x resident fp32 x0 rows, RNE-pack), then
// C-chained MFMAs. Refill BP + ONE dwordx4 xl vector for tile I+2.
#define KITER(I, SLOT, DO_ISSUE, BP)                                           \
  {                                                                            \
    PackU Z[4];                                                                \
    _Pragma("unroll")                                                          \
    for (int f = 0; f < 4; ++f) {                                              \
      const float xs = xlv[SLOT][f];                                           \
      _Pragma("unroll")                                                        \
      for (int jj = 0; jj < 4; ++jj)                                           \
        Z[f].u[jj] = pack_rne(xs * x0v[f][2 * jj], xs * x0v[f][2 * jj + 1]);   \
    }                                                                          \
    _Pragma("unroll")                                                          \
    for (int f = 0; f < 4; ++f)                                                \
      acc[f][0] = __builtin_amdgcn_mfma_f32_16x16x32_bf16(Z[f].s, BP[0].s, acc[f][0], 0, 0, 0); \
    _Pragma("unroll")                                                          \
    for (int f = 0; f < 4; ++f)                                                \
      acc[f][1] = __builtin_amdgcn_mfma_f32_16x16x32_bf16(Z[f].s, BP[1].s, acc[f][1], 0, 0, 0); \
    if (DO_ISSUE) {                                                            \
      const u32* ib = wt + (size_t)((t0 + (I) + 2) * 4 + nq) * 512;            \
      BP[0].v = *(const u32x4*)(ib + boff0);                                   \
      BP[1].v = *(const u32x4*)(ib + boff1);                                   \
      xlv[SLOT] = *(const f32x4*)(xt + (size_t)(t0 + (I) + 2) * R_TOTAL +      \
                                  r0 + ln15 * 4);                              \
    }                                                                          \
  }

// ---------------- main layer kernel ----------------
template <int NT, bool RELU, bool STORE_X>
__global__ __launch_bounds__(512, 2) void layer_mfma(
    const float* __restrict__ xt,    // NT x R, permuted rows (see build)
    const float* __restrict__ x0t,   // 32 x R, permuted rows
    const u32* __restrict__ wt,      // NT*4 quarter images (512 u32 each)
    const float* __restrict__ bias,  // 128
    float* __restrict__ xoutT,       // 128 x R, permuted rows (if STORE_X)
    float* __restrict__ osum)        // d_out + layer offset, stride 384
{
  constexpr int HT = NT / 2;
  static_assert((HT & 1) == 0 && HT >= 4, "pair-loop needs even HT >= 4");
  __shared__ u32 smem[16384];        // 64 KB: epilogue exchange only

  const int tid = threadIdx.x;
  const int w = tid >> 6, lane = tid & 63;
  const int ln15 = lane & 15, q = lane >> 4;
  const int kh = w & 1, nq = w >> 1;
  const int r0 = blockIdx.x * 64;
  const int sw = ln15 & 3;           // matches prep's 4-position XOR layout
  u32* mybuf = smem + w * 2048;

  // per-lane B-frag offsets within a 512-u32 image (loop-invariant)
  const int boff0 = ln15 * 16 + ((q ^ sw) * 4);
  const int boff1 = (16 + ln15) * 16 + ((q ^ sw) * 4);

  // ---- loop-invariant x0 rows in FP32 (A-rows i=ln15, k=q*8+j): 32 VGPR ----
  // permuted layout: logical row f*16+ln15 lives at r0 + ln15*4 + f.
  float x0v[4][8];
  #pragma unroll
  for (int f = 0; f < 4; ++f) {
    #pragma unroll
    for (int j = 0; j < 8; ++j)
      x0v[f][j] = x0t[(size_t)(q * 8 + j) * R_TOTAL + r0 + ln15 * 4 + f];
  }

  f32x4 acc[4][2];
  #pragma unroll
  for (int f = 0; f < 4; ++f)
    #pragma unroll
    for (int c = 0; c < 2; ++c) acc[f][c] = f32x4{0.f, 0.f, 0.f, 0.f};

  const int t0 = kh * HT;

  // ---- prologue: group(0) -> (ba, xlv[0]), group(1) -> (bb, xlv[1]) ----
  PackB ba[2], bb[2];
  f32x4 xlv[2];
  {
    const u32* ib = wt + (size_t)(t0 * 4 + nq) * 512;
    ba[0].v = *(const u32x4*)(ib + boff0);
    ba[1].v = *(const u32x4*)(ib + boff1);
    xlv[0] = *(const f32x4*)(xt + (size_t)t0 * R_TOTAL + r0 + ln15 * 4);
  }
  {
    const u32* ib = wt + (size_t)((t0 + 1) * 4 + nq) * 512;
    bb[0].v = *(const u32x4*)(ib + boff0);
    bb[1].v = *(const u32x4*)(ib + boff1);
    xlv[1] = *(const f32x4*)(xt + (size_t)(t0 + 1) * R_TOTAL + r0 + ln15 * 4);
  }

  // ---- steady state: consume slot, refill with tile i+2 ----
  for (int i = 0; i < HT - 2; i += 2) {
    KITER(i,     0, 1, ba);
    KITER(i + 1, 1, 1, bb);
  }
  // ---- peeled last pair: no refill ----
  KITER(HT - 2, 0, 0, ba);
  KITER(HT - 1, 1, 0, bb);

  // ---------------- epilogue ----------------
  __syncthreads();
  if (kh == 1) {                    // dump partial acc into own region (8 KB)
    u32* reg = mybuf;
    #pragma unroll
    for (int f = 0; f < 4; ++f)
      #pragma unroll
      for (int c = 0; c < 2; ++c)
        *(f32x4*)(reg + ((size_t)(f * 2 + c) * 64 + lane) * 4) = acc[f][c];
  }
  __syncthreads();
  if (kh == 0) {
    const u32* reg = smem + (w + 1) * 2048;   // partner (kh=1, same nq)
    float bs[2];
    #pragma unroll
    for (int c = 0; c < 2; ++c) bs[c] = bias[nq * 32 + c * 16 + ln15];

    f32x4 vv[4][2];
    #pragma unroll
    for (int f = 0; f < 4; ++f) {
      #pragma unroll
      for (int c = 0; c < 2; ++c) {
        f32x4 part = *(const f32x4*)(reg + ((size_t)(f * 2 + c) * 64 + lane) * 4);
        f32x4 v = acc[f][c] + part;
        v.x += bs[c]; v.y += bs[c]; v.z += bs[c]; v.w += bs[c];
        if (RELU) {
          v.x = fmaxf(v.x, 0.f); v.y = fmaxf(v.y, 0.f);
          v.z = fmaxf(v.z, 0.f); v.w = fmaxf(v.w, 0.f);
        }
        vv[f][c] = v;
        float s = v.x + v.y + v.z + v.w;       // 4 rows of batch (r0>>4)+f
        s += __shfl_xor(s, 16, 64);
        s += __shfl_xor(s, 32, 64);
        if (q == 0)
          osum[(size_t)((r0 >> 4) + f) * 384 + nq * 32 + c * 16 + ln15] = s;
      }
    }

    if (STORE_X) {
      // write XT in PERMUTED layout: element (r=f*16+i15, col) goes to
      // xoutT[col*R + r0 + i15*4 + f] -> per (col,i15) one 16B store (f=0..3).
      // Route through own LDS region (standard dump layout), gather 4 scalars.
      u32* myreg = mybuf;
      #pragma unroll
      for (int f = 0; f < 4; ++f)
        #pragma unroll
        for (int c = 0; c < 2; ++c)
          *(f32x4*)(myreg + ((size_t)(f * 2 + c) * 64 + lane) * 4) = vv[f][c];
      // dump layout: element (r=f*16+q'*4+e, col=c*16+l15') at u32 addr
      // (f*2+c)*256 + (q'*16+l15')*4 + e.
      const int i15 = lane & 15;
      #pragma unroll
      for (int c = 0; c < 2; ++c) {
        #pragma unroll
        for (int rr = 0; rr < 4; ++rr) {
          const int colIdx = (lane >> 4) + rr * 4;   // 0..15
          float o[4];
          #pragma unroll
          for (int f = 0; f < 4; ++f)
            o[f] = *(const float*)(myreg + (size_t)(f * 2 + c) * 256 +
                                   ((i15 >> 2) * 16 + colIdx) * 4 + (i15 & 3));
          const int col = nq * 32 + c * 16 + colIdx;
          *(f32x4*)&xoutT[(size_t)col * R_TOTAL + r0 + i15 * 4] =
              f32x4{o[0], o[1], o[2], o[3]};
        }
      }
    }
  }
}

extern "C" void kernel_launch(void* const* d_in, const int* in_sizes, int n_in,
                              void* d_out, int out_size, void* d_ws, size_t ws_size,
                              hipStream_t stream) {
  const float* in = (const float*)d_in[0];
  const float* W0 = (const float*)d_in[1];
  const float* b0 = (const float*)d_in[2];
  const float* W1 = (const float*)d_in[3];
  const float* b1 = (const float*)d_in[4];
  const float* W2 = (const float*)d_in[5];
  const float* b2 = (const float*)d_in[6];
  float* out = (float*)d_out;

  float* X0T = (float*)d_ws;                         // 32 x 16384   (2 MB)
  float* X1T = X0T + (size_t)32 * R_TOTAL;           // 128 x 16384  (8 MB)
  float* X2T = X1T + (size_t)128 * R_TOTAL;          // 128 x 16384  (8 MB)
  u32* Wt0 = (u32*)(X2T + (size_t)128 * R_TOTAL);    // 32*4*512 u32   (256 KB)
  u32* Wt1 = Wt0 + (size_t)32 * 4 * 512;             // 128*4*512 u32  (1 MB)
  u32* Wt2 = Wt1 + (size_t)128 * 4 * 512;            // 128*4*512 u32  (1 MB)
  // total ws: ~20.3 MB

  prep_all<<<1280, 256, 0, stream>>>(in, X0T, W0, Wt0, W1, Wt1, W2, Wt2);

  layer_mfma<32, true, true><<<256, 512, 0, stream>>>(X0T, X0T, Wt0, b0, X1T, out + 0);
  layer_mfma<128, true, true><<<256, 512, 0, stream>>>(X1T, X0T, Wt1, b1, X2T, out + 128);
  layer_mfma<128, false, false><<<256, 512, 0, stream>>>(X2T, X0T, Wt2, b2, nullptr, out + 256);
}

// Round 21
// 118.328 us; speedup vs baseline: 1.2064x; 1.0862x over previous
//
#include <hip/hip_runtime.h>

// CIN_51539607712 — R22: FUSED 3-layer kernel, activations in LDS.
// Key structural fact (unused for 21 rounds): the layer dependency is
// BLOCK-LOCAL — block b writes xoutT[col][r0..r0+63] for all cols, and the
// next layer's block b reads exactly that range. So fuse L0+L1+L2 into one
// kernel: per-block activation tile = 128 cols x 64 rows x 4B = 32 KB in
// LDS (permuted layout, R21 mapping), beside a 32 KB epilogue-dump region
// (= 64 KB exactly). Phase 0 reads xl from global X0T; epilogues write act
// to LDS; phases 1-2 read xl via one ds_read_b128 per h. Removes 2 launch
// gaps + 16 MB HBM writes + 16 MB reads of activation transport.
// K-loop per phase = R21 champion: z-GEMM (acc = mfma(rne(xl*x0), W, acc)),
// fence-free depth-2 direct-load pipeline, 2 B-loads + 1 xl-load per h.
// Numerics = R14/R20 (absmax 0.125 vs thr 0.4525). Geometry: grid 256,
// 512 thr, 8 waves (kh = w&1 K-half, nq = w>>1 N-quarter), 64-row blocks.
// out[r,n] = sum_h xl[r,h] * sum_m x0[r,m] W[h*32+m,n].

typedef unsigned int u32;
typedef __attribute__((ext_vector_type(8))) short short8;
typedef __attribute__((ext_vector_type(4))) float f32x4;
typedef __attribute__((ext_vector_type(4))) u32 u32x4;

#define R_TOTAL 16384

union PackU { u32 u[4]; short8 s; };
union PackB { u32x4 v; short8 s; };

// pack with round-to-nearest-even
__device__ __forceinline__ u32 pack_rne(float a, float b) {
  u32 r;
  asm("v_cvt_pk_bf16_f32 %0, %1, %2" : "=v"(r) : "v"(a), "v"(b));
  return r;
}

// ---------------- fused prep kernel ----------------
// blocks 0..127: build X0T (permuted: within each 64-row group, logical row
// f*16+i15 stored at i15*4+f). blocks 128+: swizzle W0/W1/W2.
__device__ __forceinline__ void build_x0t_body(const float* __restrict__ in,
                                               float* __restrict__ x0t,
                                               int bid, int tid, float* t) {
  const int b0 = bid * 8;
  #pragma unroll
  for (int rep = 0; rep < 4; ++rep) {
    int idx = tid + rep * 256;
    *(float4*)&t[idx * 4] = *(const float4*)&in[(size_t)b0 * 512 + idx * 4];
  }
  __syncthreads();
  #pragma unroll
  for (int rep = 0; rep < 4; ++rep) {
    int idx = tid + rep * 256;     // 0..1023: m(32) x bl(8) x dq(4)
    int m = idx >> 5, rem = idx & 31;
    int bl = rem >> 2, dq = rem & 3;
    float4 v = *(const float4*)&t[bl * 512 + m * 16 + dq * 4];
    const int rb = b0 + bl;
    float* dst = &x0t[(size_t)m * R_TOTAL + (rb >> 2) * 64 + (rb & 3)];
    dst[(dq * 4 + 0) * 4] = v.x;
    dst[(dq * 4 + 1) * 4] = v.y;
    dst[(dq * 4 + 2) * 4] = v.z;
    dst[(dq * 4 + 3) * 4] = v.w;
  }
}

// Block (t = bid>>2, nq = bid&3). 2 KB image: [nl 0..31][p 0..3] 16B blocks;
// position p holds logical block q = p ^ (nl&3); block q = RNE-packed
// W[t*32+q*8+j][nq*32+nl], j pairs packed (even=lo half, odd=hi half).
__device__ __forceinline__ void swizzle_body(const float* __restrict__ W,
                                             u32* __restrict__ wt,
                                             int bid, int tid, float* wl) {
  const int t = bid >> 2, nq = bid & 3;
  {
    int kk = tid >> 3, c4 = tid & 7;
    float4 v = *(const float4*)&W[(size_t)(t * 32 + kk) * 128 + nq * 32 + c4 * 4];
    wl[kk * 33 + c4 * 4 + 0] = v.x;
    wl[kk * 33 + c4 * 4 + 1] = v.y;
    wl[kk * 33 + c4 * 4 + 2] = v.z;
    wl[kk * 33 + c4 * 4 + 3] = v.w;
  }
  __syncthreads();
  if (tid < 128) {
    int nl = tid >> 2, p = tid & 3;
    int q = p ^ (nl & 3);
    u32 o[4];
    #pragma unroll
    for (int jj = 0; jj < 4; ++jj)
      o[jj] = pack_rne(wl[(q * 8 + 2 * jj + 0) * 33 + nl],
                       wl[(q * 8 + 2 * jj + 1) * 33 + nl]);
    *(u32x4*)(wt + (size_t)(t * 4 + nq) * 512 + nl * 16 + p * 4) =
        u32x4{o[0], o[1], o[2], o[3]};
  }
}

__global__ __launch_bounds__(256) void prep_all(
    const float* __restrict__ in, float* __restrict__ x0t,
    const float* __restrict__ W0, u32* __restrict__ wt0,
    const float* __restrict__ W1, u32* __restrict__ wt1,
    const float* __restrict__ W2, u32* __restrict__ wt2) {
  __shared__ float sh[4096];
  const int b = blockIdx.x, tid = threadIdx.x;
  if (b < 128)      build_x0t_body(in, x0t, b, tid, sh);
  else if (b < 256) swizzle_body(W0, wt0, b - 128, tid, sh);
  else if (b < 768) swizzle_body(W1, wt1, b - 256, tid, sh);
  else              swizzle_body(W2, wt2, b - 768, tid, sh);
}

// ---------------- one fused layer phase ----------------
// XL_LDS=false: xl from global xg (permuted, R21). XL_LDS=true: xl from LDS
// act buffer al (permuted: act[col*64 + i15*4 + f] = X[f*16+i15][col]).
// Epilogue: kh=1 dumps acc to dump region; kh=0 reduces + bias/relu, writes
// osum, and (STORE_X) writes new activations into actW (LDS, permuted).
// Caller must __syncthreads() between phases.
template <int NT, bool RELU, bool STORE_X, bool XL_LDS>
__device__ __forceinline__ void run_phase(
    const float* __restrict__ xg, const float* al,
    const u32* __restrict__ wt, const float* __restrict__ bias,
    float* __restrict__ osum, u32* smem, float* actW,
    const float (&x0v)[4][8],
    int w, int lane, int ln15, int q, int kh, int nq, int r0,
    int boff0, int boff1)
{
  constexpr int HT = NT / 2;
  static_assert((HT & 1) == 0 && HT >= 4, "pair-loop needs even HT >= 4");

  f32x4 acc[4][2];
  #pragma unroll
  for (int f = 0; f < 4; ++f)
    #pragma unroll
    for (int c = 0; c < 2; ++c) acc[f][c] = f32x4{0.f, 0.f, 0.f, 0.f};

  const int t0 = kh * HT;

  PackB ba[2], bb[2];
  f32x4 xlv[2];
  {
    const u32* ib = wt + (size_t)(t0 * 4 + nq) * 512;
    ba[0].v = *(const u32x4*)(ib + boff0);
    ba[1].v = *(const u32x4*)(ib + boff1);
    if constexpr (XL_LDS) xlv[0] = *(const f32x4*)(al + t0 * 64 + ln15 * 4);
    else xlv[0] = *(const f32x4*)(xg + (size_t)t0 * R_TOTAL + r0 + ln15 * 4);
  }
  {
    const u32* ib = wt + (size_t)((t0 + 1) * 4 + nq) * 512;
    bb[0].v = *(const u32x4*)(ib + boff0);
    bb[1].v = *(const u32x4*)(ib + boff1);
    if constexpr (XL_LDS) xlv[1] = *(const f32x4*)(al + (t0 + 1) * 64 + ln15 * 4);
    else xlv[1] = *(const f32x4*)(xg + (size_t)(t0 + 1) * R_TOTAL + r0 + ln15 * 4);
  }

  auto kit = [&](int I, int SLOT, bool issue, PackB (&BP)[2]) {
    PackU Z[4];
    #pragma unroll
    for (int f = 0; f < 4; ++f) {
      const float xs = xlv[SLOT][f];
      #pragma unroll
      for (int jj = 0; jj < 4; ++jj)
        Z[f].u[jj] = pack_rne(xs * x0v[f][2 * jj], xs * x0v[f][2 * jj + 1]);
    }
    #pragma unroll
    for (int f = 0; f < 4; ++f)
      acc[f][0] = __builtin_amdgcn_mfma_f32_16x16x32_bf16(Z[f].s, BP[0].s, acc[f][0], 0, 0, 0);
    #pragma unroll
    for (int f = 0; f < 4; ++f)
      acc[f][1] = __builtin_amdgcn_mfma_f32_16x16x32_bf16(Z[f].s, BP[1].s, acc[f][1], 0, 0, 0);
    if (issue) {
      const int t = t0 + I + 2;
      const u32* ib = wt + (size_t)(t * 4 + nq) * 512;
      BP[0].v = *(const u32x4*)(ib + boff0);
      BP[1].v = *(const u32x4*)(ib + boff1);
      if constexpr (XL_LDS) xlv[SLOT] = *(const f32x4*)(al + t * 64 + ln15 * 4);
      else xlv[SLOT] = *(const f32x4*)(xg + (size_t)t * R_TOTAL + r0 + ln15 * 4);
    }
  };

  for (int i = 0; i < HT - 2; i += 2) {
    kit(i, 0, true, ba);
    kit(i + 1, 1, true, bb);
  }
  kit(HT - 2, 0, false, ba);
  kit(HT - 1, 1, false, bb);

  // ---------------- epilogue ----------------
  __syncthreads();                  // all K-loop act reads done
  u32* dmp = smem + (size_t)(w >> 1) * 2048;
  if (kh == 1) {
    #pragma unroll
    for (int f = 0; f < 4; ++f)
      #pragma unroll
      for (int c = 0; c < 2; ++c)
        *(f32x4*)(dmp + ((size_t)(f * 2 + c) * 64 + lane) * 4) = acc[f][c];
  }
  __syncthreads();
  if (kh == 0) {
    float bs[2];
    #pragma unroll
    for (int c = 0; c < 2; ++c) bs[c] = bias[nq * 32 + c * 16 + ln15];
    #pragma unroll
    for (int f = 0; f < 4; ++f) {
      #pragma unroll
      for (int c = 0; c < 2; ++c) {
        f32x4 part = *(const f32x4*)(dmp + ((size_t)(f * 2 + c) * 64 + lane) * 4);
        f32x4 v = acc[f][c] + part;
        v.x += bs[c]; v.y += bs[c]; v.z += bs[c]; v.w += bs[c];
        if (RELU) {
          v.x = fmaxf(v.x, 0.f); v.y = fmaxf(v.y, 0.f);
          v.z = fmaxf(v.z, 0.f); v.w = fmaxf(v.w, 0.f);
        }
        float s = v.x + v.y + v.z + v.w;       // 4 rows of batch (r0>>4)+f
        s += __shfl_xor(s, 16, 64);
        s += __shfl_xor(s, 32, 64);
        if (q == 0)
          osum[(size_t)((r0 >> 4) + f) * 384 + nq * 32 + c * 16 + ln15] = s;
        if (STORE_X) {
          // element (r_local = f*16 + q*4 + rr, col = nq*32 + c*16 + ln15)
          // -> permuted act[col*64 + (q*4+rr)*4 + f]
          const int colb = (nq * 32 + c * 16 + ln15) * 64 + f;
          #pragma unroll
          for (int rr = 0; rr < 4; ++rr)
            actW[colb + (q * 4 + rr) * 4] = v[rr];
        }
      }
    }
  }
}

// ---------------- fused 3-layer kernel ----------------
// LDS 64 KB: [0, 8192) u32 = dump (4 regions x 2048 u32, shared by wave pair
// (w>>1)); [8192, 16384) u32 = act buffer (128 cols x 64 rows fp32, permuted).
__global__ __launch_bounds__(512, 2) void fused_cin(
    const float* __restrict__ x0t,
    const u32* __restrict__ wt0, const u32* __restrict__ wt1,
    const u32* __restrict__ wt2,
    const float* __restrict__ b0, const float* __restrict__ b1,
    const float* __restrict__ b2,
    float* __restrict__ out)
{
  __shared__ u32 smem[16384];

  const int tid = threadIdx.x;
  const int w = tid >> 6, lane = tid & 63;
  const int ln15 = lane & 15, q = lane >> 4;
  const int kh = w & 1, nq = w >> 1;
  const int r0 = blockIdx.x * 64;
  const int sw = ln15 & 3;

  const int boff0 = ln15 * 16 + ((q ^ sw) * 4);
  const int boff1 = (16 + ln15) * 16 + ((q ^ sw) * 4);

  float* actF = (float*)(smem + 8192);

  // ---- loop-invariant x0 rows in FP32 (A-rows i=ln15, k=q*8+j): 32 VGPR ----
  float x0v[4][8];
  #pragma unroll
  for (int f = 0; f < 4; ++f)
    #pragma unroll
    for (int j = 0; j < 8; ++j)
      x0v[f][j] = x0t[(size_t)(q * 8 + j) * R_TOTAL + r0 + ln15 * 4 + f];

  run_phase<32, true, true, false>(x0t, nullptr, wt0, b0, out + 0,
                                   smem, actF, x0v,
                                   w, lane, ln15, q, kh, nq, r0, boff0, boff1);
  __syncthreads();                  // act(L1) visible to all waves
  run_phase<128, true, true, true>(nullptr, actF, wt1, b1, out + 128,
                                   smem, actF, x0v,
                                   w, lane, ln15, q, kh, nq, r0, boff0, boff1);
  __syncthreads();                  // act(L2) visible
  run_phase<128, false, false, true>(nullptr, actF, wt2, b2, out + 256,
                                     smem, actF, x0v,
                                     w, lane, ln15, q, kh, nq, r0, boff0, boff1);
}

extern "C" void kernel_launch(void* const* d_in, const int* in_sizes, int n_in,
                              void* d_out, int out_size, void* d_ws, size_t ws_size,
                              hipStream_t stream) {
  const float* in = (const float*)d_in[0];
  const float* W0 = (const float*)d_in[1];
  const float* b0 = (const float*)d_in[2];
  const float* W1 = (const float*)d_in[3];
  const float* b1 = (const float*)d_in[4];
  const float* W2 = (const float*)d_in[5];
  const float* b2 = (const float*)d_in[6];
  float* out = (float*)d_out;

  float* X0T = (float*)d_ws;                         // 32 x 16384  (2 MB)
  u32* Wt0 = (u32*)(X0T + (size_t)32 * R_TOTAL);     // 32*4*512 u32  (256 KB)
  u32* Wt1 = Wt0 + (size_t)32 * 4 * 512;             // 128*4*512 u32 (1 MB)
  u32* Wt2 = Wt1 + (size_t)128 * 4 * 512;            // 128*4*512 u32 (1 MB)
  // total ws: ~4.25 MB

  prep_all<<<1280, 256, 0, stream>>>(in, X0T, W0, Wt0, W1, Wt1, W2, Wt2);

  fused_cin<<<256, 512, 0, stream>>>(X0T, Wt0, Wt1, Wt2, b0, b1, b2, out);
}

// Round 22
// 114.389 us; speedup vs baseline: 1.2479x; 1.0344x over previous
//
#include <hip/hip_runtime.h>

// CIN_51539607712 — R23: f16 datapath (R22 fused kernel, bf16 -> f16).
// R22's counters: VALUBusy 51% — the z-build (32 v_mul_f32 + 16 cvt_pk per
// h-step per wave) is the bottleneck. f16 fix: mfma_f32_16x16x32_f16 runs at
// the bf16 rate, and v_pk_mul_f16 builds the A-frag in packed halves:
// per f = 1 v_cvt_f16_f32 + 1 v_perm (xs->half2 bcast) + 4 v_pk_mul_f16
// -> 24 VALU ops/h (was 48). W prep packs f16 RNE (identical bit layout to
// the verified bf16 packing, so operand mapping is unchanged). Numerics
// IMPROVE: f16 rel err 2^-11 vs bf16 2^-8 (range safe: |z|<~250, |W|<~0.3).
// Everything else = R22: fused 3 layers, act tile in LDS (32 KB permuted) +
// 32 KB dump; z-GEMM fence-free depth-2 pipeline; grid 256, 512 thr,
// 8 waves (kh = w&1, nq = w>>1), 64-row blocks.
// out[r,n] = sum_h xl[r,h] * sum_m x0[r,m] W[h*32+m,n].

typedef unsigned int u32;
typedef __attribute__((ext_vector_type(8))) _Float16 half8;
typedef __attribute__((ext_vector_type(4))) float f32x4;
typedef __attribute__((ext_vector_type(4))) u32 u32x4;

#define R_TOTAL 16384

union PackH { u32 u[4]; half8 h; };
union PackB { u32x4 v; half8 h; };

// pack two floats into one u32 of f16 pairs (RNE), low half = a
__device__ __forceinline__ u32 pack_f16(float a, float b) {
  u32 ha, hb;
  asm("v_cvt_f16_f32 %0, %1" : "=v"(ha) : "v"(a));
  asm("v_cvt_f16_f32 %0, %1" : "=v"(hb) : "v"(b));
  return __builtin_amdgcn_perm(hb, ha, 0x05040100u);
}

// ---------------- fused prep kernel ----------------
// blocks 0..127: build X0T (permuted: within each 64-row group, logical row
// f*16+i15 stored at i15*4+f). blocks 128+: swizzle W0/W1/W2 (f16 images).
__device__ __forceinline__ void build_x0t_body(const float* __restrict__ in,
                                               float* __restrict__ x0t,
                                               int bid, int tid, float* t) {
  const int b0 = bid * 8;
  #pragma unroll
  for (int rep = 0; rep < 4; ++rep) {
    int idx = tid + rep * 256;
    *(float4*)&t[idx * 4] = *(const float4*)&in[(size_t)b0 * 512 + idx * 4];
  }
  __syncthreads();
  #pragma unroll
  for (int rep = 0; rep < 4; ++rep) {
    int idx = tid + rep * 256;     // 0..1023: m(32) x bl(8) x dq(4)
    int m = idx >> 5, rem = idx & 31;
    int bl = rem >> 2, dq = rem & 3;
    float4 v = *(const float4*)&t[bl * 512 + m * 16 + dq * 4];
    const int rb = b0 + bl;
    float* dst = &x0t[(size_t)m * R_TOTAL + (rb >> 2) * 64 + (rb & 3)];
    dst[(dq * 4 + 0) * 4] = v.x;
    dst[(dq * 4 + 1) * 4] = v.y;
    dst[(dq * 4 + 2) * 4] = v.z;
    dst[(dq * 4 + 3) * 4] = v.w;
  }
}

// Block (t = bid>>2, nq = bid&3). 2 KB image: [nl 0..31][p 0..3] 16B blocks;
// position p holds logical block q = p ^ (nl&3); block q = f16-RNE-packed
// W[t*32+q*8+j][nq*32+nl], j pairs packed (even=lo half, odd=hi half).
__device__ __forceinline__ void swizzle_body(const float* __restrict__ W,
                                             u32* __restrict__ wt,
                                             int bid, int tid, float* wl) {
  const int t = bid >> 2, nq = bid & 3;
  {
    int kk = tid >> 3, c4 = tid & 7;
    float4 v = *(const float4*)&W[(size_t)(t * 32 + kk) * 128 + nq * 32 + c4 * 4];
    wl[kk * 33 + c4 * 4 + 0] = v.x;
    wl[kk * 33 + c4 * 4 + 1] = v.y;
    wl[kk * 33 + c4 * 4 + 2] = v.z;
    wl[kk * 33 + c4 * 4 + 3] = v.w;
  }
  __syncthreads();
  if (tid < 128) {
    int nl = tid >> 2, p = tid & 3;
    int q = p ^ (nl & 3);
    u32 o[4];
    #pragma unroll
    for (int jj = 0; jj < 4; ++jj)
      o[jj] = pack_f16(wl[(q * 8 + 2 * jj + 0) * 33 + nl],
                       wl[(q * 8 + 2 * jj + 1) * 33 + nl]);
    *(u32x4*)(wt + (size_t)(t * 4 + nq) * 512 + nl * 16 + p * 4) =
        u32x4{o[0], o[1], o[2], o[3]};
  }
}

__global__ __launch_bounds__(256) void prep_all(
    const float* __restrict__ in, float* __restrict__ x0t,
    const float* __restrict__ W0, u32* __restrict__ wt0,
    const float* __restrict__ W1, u32* __restrict__ wt1,
    const float* __restrict__ W2, u32* __restrict__ wt2) {
  __shared__ float sh[4096];
  const int b = blockIdx.x, tid = threadIdx.x;
  if (b < 128)      build_x0t_body(in, x0t, b, tid, sh);
  else if (b < 256) swizzle_body(W0, wt0, b - 128, tid, sh);
  else if (b < 768) swizzle_body(W1, wt1, b - 256, tid, sh);
  else              swizzle_body(W2, wt2, b - 768, tid, sh);
}

// ---------------- one fused layer phase ----------------
// XL_LDS=false: xl from global xg (permuted, f32). XL_LDS=true: xl from LDS
// act buffer al (permuted f32: act[col*64 + i15*4 + f] = X[f*16+i15][col]).
// z-build: xs -> half2 broadcast, 4 v_pk_mul_f16 against resident packed-f16
// x0 rows; acc = mfma_f16(z, W, acc). Epilogue as R22.
template <int NT, bool RELU, bool STORE_X, bool XL_LDS>
__device__ __forceinline__ void run_phase(
    const float* __restrict__ xg, const float* al,
    const u32* __restrict__ wt, const float* __restrict__ bias,
    float* __restrict__ osum, u32* smem, float* actW,
    const PackH (&x0h)[4],
    int w, int lane, int ln15, int q, int kh, int nq, int r0,
    int boff0, int boff1)
{
  constexpr int HT = NT / 2;
  static_assert((HT & 1) == 0 && HT >= 4, "pair-loop needs even HT >= 4");

  f32x4 acc[4][2];
  #pragma unroll
  for (int f = 0; f < 4; ++f)
    #pragma unroll
    for (int c = 0; c < 2; ++c) acc[f][c] = f32x4{0.f, 0.f, 0.f, 0.f};

  const int t0 = kh * HT;

  PackB ba[2], bb[2];
  f32x4 xlv[2];
  {
    const u32* ib = wt + (size_t)(t0 * 4 + nq) * 512;
    ba[0].v = *(const u32x4*)(ib + boff0);
    ba[1].v = *(const u32x4*)(ib + boff1);
    if constexpr (XL_LDS) xlv[0] = *(const f32x4*)(al + t0 * 64 + ln15 * 4);
    else xlv[0] = *(const f32x4*)(xg + (size_t)t0 * R_TOTAL + r0 + ln15 * 4);
  }
  {
    const u32* ib = wt + (size_t)((t0 + 1) * 4 + nq) * 512;
    bb[0].v = *(const u32x4*)(ib + boff0);
    bb[1].v = *(const u32x4*)(ib + boff1);
    if constexpr (XL_LDS) xlv[1] = *(const f32x4*)(al + (t0 + 1) * 64 + ln15 * 4);
    else xlv[1] = *(const f32x4*)(xg + (size_t)(t0 + 1) * R_TOTAL + r0 + ln15 * 4);
  }

  auto kit = [&](int I, int SLOT, bool issue, PackB (&BP)[2]) {
    PackH Z[4];
    #pragma unroll
    for (int f = 0; f < 4; ++f) {
      u32 xs2;
      asm("v_cvt_f16_f32 %0, %1" : "=v"(xs2) : "v"(xlv[SLOT][f]));
      xs2 = __builtin_amdgcn_perm(xs2, xs2, 0x01000100u);
      #pragma unroll
      for (int jj = 0; jj < 4; ++jj)
        asm("v_pk_mul_f16 %0, %1, %2"
            : "=v"(Z[f].u[jj]) : "v"(xs2), "v"(x0h[f].u[jj]));
    }
    #pragma unroll
    for (int f = 0; f < 4; ++f)
      acc[f][0] = __builtin_amdgcn_mfma_f32_16x16x32_f16(Z[f].h, BP[0].h, acc[f][0], 0, 0, 0);
    #pragma unroll
    for (int f = 0; f < 4; ++f)
      acc[f][1] = __builtin_amdgcn_mfma_f32_16x16x32_f16(Z[f].h, BP[1].h, acc[f][1], 0, 0, 0);
    if (issue) {
      const int t = t0 + I + 2;
      const u32* ib = wt + (size_t)(t * 4 + nq) * 512;
      BP[0].v = *(const u32x4*)(ib + boff0);
      BP[1].v = *(const u32x4*)(ib + boff1);
      if constexpr (XL_LDS) xlv[SLOT] = *(const f32x4*)(al + t * 64 + ln15 * 4);
      else xlv[SLOT] = *(const f32x4*)(xg + (size_t)t * R_TOTAL + r0 + ln15 * 4);
    }
  };

  for (int i = 0; i < HT - 2; i += 2) {
    kit(i, 0, true, ba);
    kit(i + 1, 1, true, bb);
  }
  kit(HT - 2, 0, false, ba);
  kit(HT - 1, 1, false, bb);

  // ---------------- epilogue ----------------
  __syncthreads();                  // all K-loop act reads done
  u32* dmp = smem + (size_t)(w >> 1) * 2048;
  if (kh == 1) {
    #pragma unroll
    for (int f = 0; f < 4; ++f)
      #pragma unroll
      for (int c = 0; c < 2; ++c)
        *(f32x4*)(dmp + ((size_t)(f * 2 + c) * 64 + lane) * 4) = acc[f][c];
  }
  __syncthreads();
  if (kh == 0) {
    float bs[2];
    #pragma unroll
    for (int c = 0; c < 2; ++c) bs[c] = bias[nq * 32 + c * 16 + ln15];
    #pragma unroll
    for (int f = 0; f < 4; ++f) {
      #pragma unroll
      for (int c = 0; c < 2; ++c) {
        f32x4 part = *(const f32x4*)(dmp + ((size_t)(f * 2 + c) * 64 + lane) * 4);
        f32x4 v = acc[f][c] + part;
        v.x += bs[c]; v.y += bs[c]; v.z += bs[c]; v.w += bs[c];
        if (RELU) {
          v.x = fmaxf(v.x, 0.f); v.y = fmaxf(v.y, 0.f);
          v.z = fmaxf(v.z, 0.f); v.w = fmaxf(v.w, 0.f);
        }
        float s = v.x + v.y + v.z + v.w;       // 4 rows of batch (r0>>4)+f
        s += __shfl_xor(s, 16, 64);
        s += __shfl_xor(s, 32, 64);
        if (q == 0)
          osum[(size_t)((r0 >> 4) + f) * 384 + nq * 32 + c * 16 + ln15] = s;
        if (STORE_X) {
          // element (r_local = f*16 + q*4 + rr, col = nq*32 + c*16 + ln15)
          // -> permuted act[col*64 + (q*4+rr)*4 + f]
          const int colb = (nq * 32 + c * 16 + ln15) * 64 + f;
          #pragma unroll
          for (int rr = 0; rr < 4; ++rr)
            actW[colb + (q * 4 + rr) * 4] = v[rr];
        }
      }
    }
  }
}

// ---------------- fused 3-layer kernel ----------------
// LDS 64 KB: [0, 8192) u32 = dump (4 regions x 2048 u32, shared by wave pair
// (w>>1)); [8192, 16384) u32 = act buffer (128 cols x 64 rows fp32, permuted).
__global__ __launch_bounds__(512, 2) void fused_cin(
    const float* __restrict__ x0t,
    const u32* __restrict__ wt0, const u32* __restrict__ wt1,
    const u32* __restrict__ wt2,
    const float* __restrict__ b0, const float* __restrict__ b1,
    const float* __restrict__ b2,
    float* __restrict__ out)
{
  __shared__ u32 smem[16384];

  const int tid = threadIdx.x;
  const int w = tid >> 6, lane = tid & 63;
  const int ln15 = lane & 15, q = lane >> 4;
  const int kh = w & 1, nq = w >> 1;
  const int r0 = blockIdx.x * 64;
  const int sw = ln15 & 3;

  const int boff0 = ln15 * 16 + ((q ^ sw) * 4);
  const int boff1 = (16 + ln15) * 16 + ((q ^ sw) * 4);

  float* actF = (float*)(smem + 8192);

  // ---- loop-invariant x0 rows as packed f16 (A-rows i=ln15, k=q*8+j) ----
  PackH x0h[4];
  #pragma unroll
  for (int f = 0; f < 4; ++f) {
    float e[8];
    #pragma unroll
    for (int j = 0; j < 8; ++j)
      e[j] = x0t[(size_t)(q * 8 + j) * R_TOTAL + r0 + ln15 * 4 + f];
    #pragma unroll
    for (int jj = 0; jj < 4; ++jj)
      x0h[f].u[jj] = pack_f16(e[2 * jj], e[2 * jj + 1]);
  }

  run_phase<32, true, true, false>(x0t, nullptr, wt0, b0, out + 0,
                                   smem, actF, x0h,
                                   w, lane, ln15, q, kh, nq, r0, boff0, boff1);
  __syncthreads();                  // act(L1) visible to all waves
  run_phase<128, true, true, true>(nullptr, actF, wt1, b1, out + 128,
                                   smem, actF, x0h,
                                   w, lane, ln15, q, kh, nq, r0, boff0, boff1);
  __syncthreads();                  // act(L2) visible
  run_phase<128, false, false, true>(nullptr, actF, wt2, b2, out + 256,
                                     smem, actF, x0h,
                                     w, lane, ln15, q, kh, nq, r0, boff0, boff1);
}

extern "C" void kernel_launch(void* const* d_in, const int* in_sizes, int n_in,
                              void* d_out, int out_size, void* d_ws, size_t ws_size,
                              hipStream_t stream) {
  const float* in = (const float*)d_in[0];
  const float* W0 = (const float*)d_in[1];
  const float* b0 = (const float*)d_in[2];
  const float* W1 = (const float*)d_in[3];
  const float* b1 = (const float*)d_in[4];
  const float* W2 = (const float*)d_in[5];
  const float* b2 = (const float*)d_in[6];
  float* out = (float*)d_out;

  float* X0T = (float*)d_ws;                         // 32 x 16384  (2 MB)
  u32* Wt0 = (u32*)(X0T + (size_t)32 * R_TOTAL);     // 32*4*512 u32  (256 KB)
  u32* Wt1 = Wt0 + (size_t)32 * 4 * 512;             // 128*4*512 u32 (1 MB)
  u32* Wt2 = Wt1 + (size_t)128 * 4 * 512;            // 128*4*512 u32 (1 MB)
  // total ws: ~4.25 MB

  prep_all<<<1280, 256, 0, stream>>>(in, X0T, W0, Wt0, W1, Wt1, W2, Wt2);

  fused_cin<<<256, 512, 0, stream>>>(X0T, Wt0, Wt1, Wt2, b0, b1, b2, out);
}